// Round 1
// baseline (390.113 us; speedup 1.0000x reference)
//
#include <hip/hip_runtime.h>
#include <hip/hip_bf16.h>

// Problem constants (B=128, N=8, S=16, DIM=64, H=4, DH=16)
#define B_   128
#define N_   8
#define S_   16
#define DIM_ 64
#define H_   4
#define DH_  16

// dot of a contiguous 64-elem fp32 row with a 64-elem fp32 vector (regs/LDS)
__device__ __forceinline__ float dot_row64f(const float* __restrict__ row,
                                            const float* __restrict__ v) {
    const float4* rp = (const float4*)row;
    float acc = 0.f;
#pragma unroll
    for (int m = 0; m < 16; ++m) {
        float4 u = rp[m];
        acc = fmaf(u.x, v[4 * m + 0], acc);
        acc = fmaf(u.y, v[4 * m + 1], acc);
        acc = fmaf(u.z, v[4 * m + 2], acc);
        acc = fmaf(u.w, v[4 * m + 3], acc);
    }
    return acc;
}

// async global -> LDS, 16 bytes per lane; LDS dest = wave-uniform base + lane*16
__device__ __forceinline__ void load_lds16(const float* g, float* lds) {
    __builtin_amdgcn_global_load_lds(
        (const __attribute__((address_space(1))) void*)g,
        (__attribute__((address_space(3))) void*)lds,
        16, 0, 0);
}

__global__ __launch_bounds__(256) void EntityAggregator_63342177681721_kernel(
    const float* __restrict__ self_e,   // [B][N][64]
    const float* __restrict__ nghu,     // [B][S][64]
    const float* __restrict__ nghe,     // [B][N][S][64]
    const float* __restrict__ user_e,   // [B][64]
    const float* __restrict__ item_e,   // [B][64]
    const float* __restrict__ W_r,      // [B][N][S][64][64]
    const float* __restrict__ W_ui,     // [64][64]
    const float* __restrict__ lin_W,    // [64][64]
    const float* __restrict__ lin_b,    // [64]
    const float* __restrict__ linUI_W,  // [64][64]
    const float* __restrict__ linUI_b,  // [64]
    float* __restrict__ out)            // [B][N][64]
{
    const int blk  = blockIdx.x;   // = b*N_ + n
    const int b    = blk >> 3;
    const int t    = threadIdx.x;
    const int w    = t >> 6;       // wave 0..3
    const int lane = t & 63;

    // Per-wave W_r double buffers: 4 waves x 2 bufs x 1024 floats (4 KB) = 32 KB.
    // (Halved from 8 KB chunks: total LDS 78 -> ~46 KB => 3 blocks/CU instead of 2,
    //  so a third co-resident block's W_r stream covers prologue/epilogue DMA gaps.)
    __shared__ __align__(16) float sW[4 * 2 * 1024];
    __shared__ float sU[S_][DIM_ + 1];
    __shared__ float sE[S_][DIM_ + 1];
    __shared__ float sQ[S_][DIM_ + 1];
    __shared__ float sItem[DIM_];
    __shared__ float sWi[DIM_];
    __shared__ float sAtt[H_][S_];
    __shared__ float sUei[DIM_];
    __shared__ float sTi[DIM_];
    __shared__ __align__(16) float sV[DIM_];
    __shared__ float sAgg[DIM_];

    const float* Wp = W_r + (size_t)blk * (S_ * DIM_ * DIM_);  // 65536 floats (256 KB)
    // Wave w owns floats [w*16384, (w+1)*16384) = rows [w*256, w*256+256).
    // Per-wave chunk = 1024 floats (16 rows, 4 KB) = 4 DMA instructions of 1 KB.
    // 16 chunks per wave.

    // ---- pre-issue this wave's chunks 0 AND 1 (both buffers) ----
    // Keeps 8 KB/wave of DMA in flight through the prologue barriers; the
    // barriers' vmcnt(0) drain means both land before the q-loop starts.
    {
        const float* g  = Wp + w * 16384 + lane * 4;
        float* l0 = sW + (w * 2 + 0) * 1024;
        float* l1 = sW + (w * 2 + 1) * 1024;
#pragma unroll
        for (int rr = 0; rr < 4; ++rr)
            load_lds16(g + rr * 256, l0 + rr * 256);
#pragma unroll
        for (int rr = 0; rr < 4; ++rr)
            load_lds16(g + 1024 + rr * 256, l1 + rr * 256);
    }

    // ---- stage nghu[b] and nghe[b,n] into LDS ----
    {
        const int e0 = t * 4;
        const int s  = e0 >> 6;
        const int c  = e0 & 63;
        float4 uu = *(const float4*)(nghu + (size_t)b * S_ * DIM_ + e0);
        sU[s][c + 0] = uu.x; sU[s][c + 1] = uu.y;
        sU[s][c + 2] = uu.z; sU[s][c + 3] = uu.w;
        float4 ee = *(const float4*)(nghe + (size_t)blk * S_ * DIM_ + e0);
        sE[s][c + 0] = ee.x; sE[s][c + 1] = ee.y;
        sE[s][c + 2] = ee.z; sE[s][c + 3] = ee.w;
        if (t < DIM_) sItem[t] = item_e[(size_t)b * DIM_ + t];
    }
    __syncthreads();

    // ---- Wi = W_ui @ item[b] ----
    if (t < DIM_) sWi[t] = dot_row64f(W_ui + t * DIM_, sItem);
    __syncthreads();

    // ---- user attention softmax over S (wave0; lane = h*16+s) ----
    if (t < DIM_) {
        const int h = t >> 4, s = t & 15;
        float l = 0.f;
#pragma unroll
        for (int d = 0; d < DH_; ++d) l = fmaf(sWi[h * DH_ + d], sU[s][h * DH_ + d], l);
        l *= 0.25f;
        float mx = l;
#pragma unroll
        for (int off = 8; off; off >>= 1) mx = fmaxf(mx, __shfl_xor(mx, off, 16));
        float e = __expf(l - mx);
        float sm = e;
#pragma unroll
        for (int off = 8; off; off >>= 1) sm += __shfl_xor(sm, off, 16);
        sAtt[h][s] = e / sm;
    }
    __syncthreads();

    // ---- user_ego, item+ego ----
    if (t < DIM_) {
        const int h = t >> 4;
        float ego = 0.f;
#pragma unroll
        for (int s = 0; s < S_; ++s) ego = fmaf(sAtt[h][s], sU[s][t], ego);
        sUei[t] = ego;
        sTi[t]  = sItem[t] + ego;
    }
    __syncthreads();

    // ---- item_UI -> signal -> v ----
    if (t < DIM_) {
        float a   = dot_row64f(linUI_W + t * DIM_, sTi) + linUI_b[t];
        float iui = fmaxf(a, 0.f);
        float sig = user_e[(size_t)b * DIM_ + t] + iui;
        sV[t] = sig * self_e[(size_t)blk * DIM_ + t];
    }
    __syncthreads();   // also drains chunk-0/1 DMA (vmcnt 0 at q-loop entry)

    // ---- q[s,i] = W_r[b,n,s,i,:] . v ----
    // Barrier-free pipelined loop: wave w produces AND consumes its own rows.
    // vmcnt is per-wave, so s_waitcnt vmcnt(4) orders chunk c's landing without
    // any __syncthreads (which would drain the prefetch and kill the pipeline).
    // Chunks 0 and 1 were issued before the prologue, so iteration 0 issues
    // nothing; from c=1 on we issue chunk c+1 into the buffer consumed at c-1.
    {
        const int r  = lane >> 2;   // 0..15: row within chunk
        const int qt = lane & 3;    // which 16-float quarter of the row
        const float4* vv4 = (const float4*)sV;
#pragma unroll 1
        for (int c = 0; c < 16; ++c) {
            if (c >= 1 && c <= 14) {
                const float* g = Wp + w * 16384 + (c + 1) * 1024 + lane * 4;
                float* lb = sW + (w * 2 + ((c + 1) & 1)) * 1024;
#pragma unroll
                for (int rr = 0; rr < 4; ++rr)
                    load_lds16(g + rr * 256, lb + rr * 256);
            }
            if (c < 15) {
                asm volatile("s_waitcnt vmcnt(4)" ::: "memory");  // chunk c landed
            } else {
                asm volatile("s_waitcnt vmcnt(0)" ::: "memory");  // last chunk landed
            }
            const float4* bp = (const float4*)(sW + (w * 2 + (c & 1)) * 1024);
            float acc = 0.f;
#pragma unroll
            for (int m = 0; m < 4; ++m) {
                const int col4 = (qt * 4 + m + r) & 15;  // rotate: conflict-free banks
                float4 u = bp[r * 16 + col4];
                float4 v = vv4[col4];
                acc = fmaf(u.x, v.x, acc);
                acc = fmaf(u.y, v.y, acc);
                acc = fmaf(u.z, v.z, acc);
                acc = fmaf(u.w, v.w, acc);
            }
            acc += __shfl_xor(acc, 1);                // join the four quarter-rows
            acc += __shfl_xor(acc, 2);
            if (qt == 0) {
                const int rowg = w * 256 + c * 16 + r;   // = s*64 + i
                sQ[rowg >> 6][rowg & 63] = acc;
            }
        }
    }
    __syncthreads();   // publish sQ across waves

    // ---- entity attention softmax over S (wave0) ----
    if (t < DIM_) {
        const int h = t >> 4, s = t & 15;
        float l = 0.f;
#pragma unroll
        for (int d = 0; d < DH_; ++d) l = fmaf(sQ[s][h * DH_ + d], sE[s][h * DH_ + d], l);
        l *= 0.25f;
        float mx = l;
#pragma unroll
        for (int off = 8; off; off >>= 1) mx = fmaxf(mx, __shfl_xor(mx, off, 16));
        float e = __expf(l - mx);
        float sm = e;
#pragma unroll
        for (int off = 8; off; off >>= 1) sm += __shfl_xor(sm, off, 16);
        sAtt[h][s] = e / sm;
    }
    __syncthreads();

    // ---- entity_ego + aggregate ----
    if (t < DIM_) {
        const int h = t >> 4;
        float ego = 0.f;
#pragma unroll
        for (int s = 0; s < S_; ++s) ego = fmaf(sAtt[h][s], sE[s][t], ego);
        sAgg[t] = self_e[(size_t)blk * DIM_ + t] + sUei[t] + ego;
    }
    __syncthreads();

    // ---- out = relu(lin_W @ agg + lin_b) ----
    if (t < DIM_) {
        float o = dot_row64f(lin_W + t * DIM_, sAgg) + lin_b[t];
        o = fmaxf(o, 0.f);
        out[(size_t)blk * DIM_ + t] = o;
    }
}

extern "C" void kernel_launch(void* const* d_in, const int* in_sizes, int n_in,
                              void* d_out, int out_size, void* d_ws, size_t ws_size,
                              hipStream_t stream) {
    (void)in_sizes; (void)n_in; (void)d_ws; (void)ws_size; (void)out_size;
    const float* self_e  = (const float*)d_in[0];
    const float* nghu    = (const float*)d_in[1];
    const float* nghe    = (const float*)d_in[2];
    const float* user_e  = (const float*)d_in[3];
    const float* item_e  = (const float*)d_in[4];
    const float* W_r     = (const float*)d_in[5];
    const float* W_ui    = (const float*)d_in[6];
    const float* lin_W   = (const float*)d_in[7];
    const float* lin_b   = (const float*)d_in[8];
    const float* linUI_W = (const float*)d_in[9];
    const float* linUI_b = (const float*)d_in[10];

    dim3 grid(B_ * N_);
    dim3 block(256);
    hipLaunchKernelGGL(EntityAggregator_63342177681721_kernel, grid, block, 0, stream,
                       self_e, nghu, nghe, user_e, item_e, W_r, W_ui,
                       lin_W, lin_b, linUI_W, linUI_b, (float*)d_out);
}

// Round 2
// 383.920 us; speedup vs baseline: 1.0161x; 1.0161x over previous
//
#include <hip/hip_runtime.h>
#include <hip/hip_bf16.h>

// Problem constants (B=128, N=8, S=16, DIM=64, H=4, DH=16)
#define B_   128
#define N_   8
#define S_   16
#define DIM_ 64
#define H_   4
#define DH_  16

// dot of a contiguous 64-elem fp32 row with a 64-elem fp32 vector (regs/LDS)
__device__ __forceinline__ float dot_row64f(const float* __restrict__ row,
                                            const float* __restrict__ v) {
    const float4* rp = (const float4*)row;
    float acc = 0.f;
#pragma unroll
    for (int m = 0; m < 16; ++m) {
        float4 u = rp[m];
        acc = fmaf(u.x, v[4 * m + 0], acc);
        acc = fmaf(u.y, v[4 * m + 1], acc);
        acc = fmaf(u.z, v[4 * m + 2], acc);
        acc = fmaf(u.w, v[4 * m + 3], acc);
    }
    return acc;
}

__device__ __forceinline__ float fma4(float4 u, float4 v, float a) {
    a = fmaf(u.x, v.x, a);
    a = fmaf(u.y, v.y, a);
    a = fmaf(u.z, v.z, a);
    a = fmaf(u.w, v.w, a);
    return a;
}

// Load 8 float4 (one 32-float half-row) into named registers.
#define LOAD8(BUF, IT) do {                                                  \
    const float4* gp_ = (const float4*)(gbase + (IT) * 2048);                \
    BUF##0 = gp_[0]; BUF##1 = gp_[1]; BUF##2 = gp_[2]; BUF##3 = gp_[3];      \
    BUF##4 = gp_[4]; BUF##5 = gp_[5]; BUF##6 = gp_[6]; BUF##7 = gp_[7];      \
} while (0)

// Dot the buffered half-row with the register-resident v half; join the two
// half-rows via shfl; lane with half==0 publishes q[row] to sQ.
#define STEP8(BUF, IT) do {                                                  \
    float acc_ = 0.f;                                                        \
    acc_ = fma4(BUF##0, vr0, acc_); acc_ = fma4(BUF##1, vr1, acc_);          \
    acc_ = fma4(BUF##2, vr2, acc_); acc_ = fma4(BUF##3, vr3, acc_);          \
    acc_ = fma4(BUF##4, vr4, acc_); acc_ = fma4(BUF##5, vr5, acc_);          \
    acc_ = fma4(BUF##6, vr6, acc_); acc_ = fma4(BUF##7, vr7, acc_);          \
    acc_ += __shfl_xor(acc_, 1);                                             \
    if (half == 0) {                                                         \
        const int rowg_ = w * 256 + (IT) * 32 + r;   /* = s*64 + i */        \
        sQ[rowg_ >> 6][rowg_ & 63] = acc_;                                   \
    }                                                                        \
} while (0)

__global__ __launch_bounds__(256, 4) void EntityAggregator_63342177681721_kernel(
    const float* __restrict__ self_e,   // [B][N][64]
    const float* __restrict__ nghu,     // [B][S][64]
    const float* __restrict__ nghe,     // [B][N][S][64]
    const float* __restrict__ user_e,   // [B][64]
    const float* __restrict__ item_e,   // [B][64]
    const float* __restrict__ W_r,      // [B][N][S][64][64]
    const float* __restrict__ W_ui,     // [64][64]
    const float* __restrict__ lin_W,    // [64][64]
    const float* __restrict__ lin_b,    // [64]
    const float* __restrict__ linUI_W,  // [64][64]
    const float* __restrict__ linUI_b,  // [64]
    float* __restrict__ out)            // [B][N][64]
{
    const int blk  = blockIdx.x;   // = b*N_ + n
    const int b    = blk >> 3;
    const int t    = threadIdx.x;
    const int w    = t >> 6;       // wave 0..3
    const int lane = t & 63;

    // W_r is streamed straight to registers (single-use data; no LDS round
    // trip). LDS is only the small shared state: ~14 KB -> occupancy is
    // bounded by VGPRs/waves (>=4 blocks/CU at <=128 VGPR), not LDS.
    __shared__ float sU[S_][DIM_ + 1];
    __shared__ float sE[S_][DIM_ + 1];
    __shared__ float sQ[S_][DIM_ + 1];
    __shared__ float sItem[DIM_];
    __shared__ float sWi[DIM_];
    __shared__ float sAtt[H_][S_];
    __shared__ float sUei[DIM_];
    __shared__ float sTi[DIM_];
    __shared__ __align__(16) float sV[DIM_];
    __shared__ float sAgg[DIM_];

    const float* Wp = W_r + (size_t)blk * (S_ * DIM_ * DIM_);  // 65536 floats (256 KB)
    // Wave w owns rows [w*256, w*256+256) of the 1024 rows (row = s*64+i).
    // 2 lanes per row: lane = 2*r + half; each lane covers 32 columns.
    const int r    = lane >> 1;    // 0..31: row within a 32-row group
    const int half = lane & 1;     // which 32-float half of the row
    const float* gbase = Wp + (size_t)(w * 256 + r) * 64 + half * 32;
    // iteration stride: 32 rows * 64 floats = 2048 floats (8 KB per wave-iter)

    float4 a0, a1, a2, a3, a4, a5, a6, a7;   // stream buffer A
    float4 b0, b1, b2, b3, b4, b5, b6, b7;   // stream buffer B

    // Pre-issue iteration 0 of the W_r stream; it flies during the prologue.
    LOAD8(a, 0);

    // ---- stage nghu[b] and nghe[b,n] into LDS ----
    {
        const int e0 = t * 4;
        const int s  = e0 >> 6;
        const int c  = e0 & 63;
        float4 uu = *(const float4*)(nghu + (size_t)b * S_ * DIM_ + e0);
        sU[s][c + 0] = uu.x; sU[s][c + 1] = uu.y;
        sU[s][c + 2] = uu.z; sU[s][c + 3] = uu.w;
        float4 ee = *(const float4*)(nghe + (size_t)blk * S_ * DIM_ + e0);
        sE[s][c + 0] = ee.x; sE[s][c + 1] = ee.y;
        sE[s][c + 2] = ee.z; sE[s][c + 3] = ee.w;
        if (t < DIM_) sItem[t] = item_e[(size_t)b * DIM_ + t];
    }
    __syncthreads();

    // ---- Wi = W_ui @ item[b] ----
    if (t < DIM_) sWi[t] = dot_row64f(W_ui + t * DIM_, sItem);
    __syncthreads();

    // ---- user attention softmax over S (lane = h*16+s) ----
    if (t < DIM_) {
        const int h = t >> 4, s = t & 15;
        float l = 0.f;
#pragma unroll
        for (int d = 0; d < DH_; ++d) l = fmaf(sWi[h * DH_ + d], sU[s][h * DH_ + d], l);
        l *= 0.25f;
        float mx = l;
#pragma unroll
        for (int off = 8; off; off >>= 1) mx = fmaxf(mx, __shfl_xor(mx, off, 16));
        float e = __expf(l - mx);
        float sm = e;
#pragma unroll
        for (int off = 8; off; off >>= 1) sm += __shfl_xor(sm, off, 16);
        sAtt[h][s] = e / sm;
    }
    __syncthreads();

    // ---- user_ego, item+ego ----
    if (t < DIM_) {
        const int h = t >> 4;
        float ego = 0.f;
#pragma unroll
        for (int s = 0; s < S_; ++s) ego = fmaf(sAtt[h][s], sU[s][t], ego);
        sUei[t] = ego;
        sTi[t]  = sItem[t] + ego;
    }
    __syncthreads();

    // ---- item_UI -> signal -> v ----
    if (t < DIM_) {
        float a   = dot_row64f(linUI_W + t * DIM_, sTi) + linUI_b[t];
        float iui = fmaxf(a, 0.f);
        float sig = user_e[(size_t)b * DIM_ + t] + iui;
        sV[t] = sig * self_e[(size_t)blk * DIM_ + t];
    }
    __syncthreads();

    // ---- q[s,i] = W_r[b,n,s,i,:] . v ----
    // Register-streamed, barrier-free, 2-buffer software pipeline. No LDS for
    // W_r, no explicit waitcnt: the compiler's counted vmcnt waits give
    // 1-iteration-ahead overlap per wave; 16 waves/CU add TLP on top.
    {
        // v half for this lane, kept in registers (broadcast LDS read, once)
        const float4* vv4 = (const float4*)sV;
        float4 vr0 = vv4[half * 8 + 0], vr1 = vv4[half * 8 + 1];
        float4 vr2 = vv4[half * 8 + 2], vr3 = vv4[half * 8 + 3];
        float4 vr4 = vv4[half * 8 + 4], vr5 = vv4[half * 8 + 5];
        float4 vr6 = vv4[half * 8 + 6], vr7 = vv4[half * 8 + 7];

        LOAD8(b, 1);
        STEP8(a, 0); LOAD8(a, 2);
        STEP8(b, 1); LOAD8(b, 3);
        STEP8(a, 2); LOAD8(a, 4);
        STEP8(b, 3); LOAD8(b, 5);
        STEP8(a, 4); LOAD8(a, 6);
        STEP8(b, 5); LOAD8(b, 7);
        STEP8(a, 6);
        STEP8(b, 7);
    }
    __syncthreads();   // publish sQ across waves

    // ---- entity attention softmax over S ----
    if (t < DIM_) {
        const int h = t >> 4, s = t & 15;
        float l = 0.f;
#pragma unroll
        for (int d = 0; d < DH_; ++d) l = fmaf(sQ[s][h * DH_ + d], sE[s][h * DH_ + d], l);
        l *= 0.25f;
        float mx = l;
#pragma unroll
        for (int off = 8; off; off >>= 1) mx = fmaxf(mx, __shfl_xor(mx, off, 16));
        float e = __expf(l - mx);
        float sm = e;
#pragma unroll
        for (int off = 8; off; off >>= 1) sm += __shfl_xor(sm, off, 16);
        sAtt[h][s] = e / sm;
    }
    __syncthreads();

    // ---- entity_ego + aggregate ----
    if (t < DIM_) {
        const int h = t >> 4;
        float ego = 0.f;
#pragma unroll
        for (int s = 0; s < S_; ++s) ego = fmaf(sAtt[h][s], sE[s][t], ego);
        sAgg[t] = self_e[(size_t)blk * DIM_ + t] + sUei[t] + ego;
    }
    __syncthreads();

    // ---- out = relu(lin_W @ agg + lin_b) ----
    if (t < DIM_) {
        float o = dot_row64f(lin_W + t * DIM_, sAgg) + lin_b[t];
        o = fmaxf(o, 0.f);
        out[(size_t)blk * DIM_ + t] = o;
    }
}

extern "C" void kernel_launch(void* const* d_in, const int* in_sizes, int n_in,
                              void* d_out, int out_size, void* d_ws, size_t ws_size,
                              hipStream_t stream) {
    (void)in_sizes; (void)n_in; (void)d_ws; (void)ws_size; (void)out_size;
    const float* self_e  = (const float*)d_in[0];
    const float* nghu    = (const float*)d_in[1];
    const float* nghe    = (const float*)d_in[2];
    const float* user_e  = (const float*)d_in[3];
    const float* item_e  = (const float*)d_in[4];
    const float* W_r     = (const float*)d_in[5];
    const float* W_ui    = (const float*)d_in[6];
    const float* lin_W   = (const float*)d_in[7];
    const float* lin_b   = (const float*)d_in[8];
    const float* linUI_W = (const float*)d_in[9];
    const float* linUI_b = (const float*)d_in[10];

    dim3 grid(B_ * N_);
    dim3 block(256);
    hipLaunchKernelGGL(EntityAggregator_63342177681721_kernel, grid, block, 0, stream,
                       self_e, nghu, nghe, user_e, item_e, W_r, W_ui,
                       lin_W, lin_b, linUI_W, linUI_b, (float*)d_out);
}